// Round 16
// baseline (161.287 us; speedup 1.0000x reference)
//
#include <hip/hip_runtime.h>
#include <math.h>

// Graph constants for this problem size (N=100000, E=1600000).
#define VSH   9                  // nodes per bucket = 512
#define VPB   512
#define MAXB  256                // max buckets (N <= 131072)
#define CAP   12288              // per-bucket edge capacity (padded)
#define BINCH 8192               // edges per k_bin block

// GEMM tiling
#define GN    128                // nodes per block (k_l01, k_aggemm)
#define GSTR  132                // hT row stride in floats (16B-aligned; 2-way banks)
#define PSTR  132                // hP pair-row stride in unsigned (16B-aligned)

// ---------------- bf16 helpers (RNE) ----------------
__device__ __forceinline__ float bflo(unsigned u) { return __uint_as_float(u << 16); }
__device__ __forceinline__ float bfhi(unsigned u) { return __uint_as_float(u & 0xFFFF0000u); }
__device__ __forceinline__ unsigned packbf2(float a, float b) {
    unsigned ua = __float_as_uint(a);
    unsigned ub = __float_as_uint(b);
    ua += 0x7FFFu + ((ua >> 16) & 1u);   // round-to-nearest-even
    ub += 0x7FFFu + ((ub >> 16) & 1u);
    return (ua >> 16) | (ub & 0xFFFF0000u);
}

// ---------------- graph prep ----------------

// zero counters + the sentinel rows (node id == n) of A, A2 and xw
__global__ void k_zero(int* __restrict__ bktCur, int* __restrict__ gtotal,
                       unsigned short* __restrict__ tz, unsigned short* __restrict__ tz2,
                       float* __restrict__ xwz) {
    int i = threadIdx.x;
    if (i < MAXB) bktCur[i] = 0;
    if (i == 0) *gtotal = 0;
    if (i < 64) { tz[i] = 0; tz2[i] = 0; }
    if (i < 3) xwz[i] = 0.f;
}

// Bin edges by dst bucket. Per block: LDS histogram -> per-bucket global
// reservation -> LDS stage ordered by bucket -> coalesced write-out.
__global__ void k_bin(const int* __restrict__ src, const int* __restrict__ dst,
                      int* __restrict__ bktCur, int* __restrict__ binned,
                      int e, int nb) {
    __shared__ int hist[MAXB];
    __shared__ int offs[MAXB];
    __shared__ int gbase[MAXB];
    __shared__ int lcur[MAXB];
    __shared__ int stage[BINCH];
    __shared__ unsigned char binid[BINCH];
    const int tid = threadIdx.x;
    const int blockStart = blockIdx.x * BINCH;
    const int chunk = min(BINCH, e - blockStart);

    for (int b = tid; b < MAXB; b += blockDim.x) hist[b] = 0;
    __syncthreads();

    // pass 1: histogram
    for (int k = 0; k < BINCH / 1024; ++k) {
        int i0 = blockStart + k * 1024 + tid * 4;
        if (i0 + 3 < e) {
            int4 d4 = *(const int4*)(dst + i0);
            atomicAdd(&hist[d4.x >> VSH], 1);
            atomicAdd(&hist[d4.y >> VSH], 1);
            atomicAdd(&hist[d4.z >> VSH], 1);
            atomicAdd(&hist[d4.w >> VSH], 1);
        } else {
            for (int i = i0; i < e && i < i0 + 4; ++i)
                atomicAdd(&hist[dst[i] >> VSH], 1);
        }
    }
    __syncthreads();

    if (tid == 0) {
        int run = 0;
        for (int b = 0; b < nb; ++b) { offs[b] = run; run += hist[b]; }
    }
    __syncthreads();
    if (tid < nb) {
        gbase[tid] = (hist[tid] > 0) ? atomicAdd(&bktCur[tid], hist[tid]) : 0;
        lcur[tid] = offs[tid];
    }
    __syncthreads();

    // pass 2: stage ordered by bucket (re-read edges, L2-hot)
    for (int k = 0; k < BINCH / 1024; ++k) {
        int i0 = blockStart + k * 1024 + tid * 4;
        if (i0 + 3 < e) {
            int4 s4 = *(const int4*)(src + i0);
            int4 d4 = *(const int4*)(dst + i0);
            int bs[4] = { d4.x >> VSH, d4.y >> VSH, d4.z >> VSH, d4.w >> VSH };
            int pk[4] = { ((d4.x & (VPB - 1)) << 17) | s4.x,
                          ((d4.y & (VPB - 1)) << 17) | s4.y,
                          ((d4.z & (VPB - 1)) << 17) | s4.z,
                          ((d4.w & (VPB - 1)) << 17) | s4.w };
#pragma unroll
            for (int q = 0; q < 4; ++q) {
                int slot = atomicAdd(&lcur[bs[q]], 1);
                stage[slot] = pk[q];
                binid[slot] = (unsigned char)bs[q];
            }
        } else {
            for (int i = i0; i < e && i < i0 + 4; ++i) {
                int d = dst[i], b = d >> VSH;
                int slot = atomicAdd(&lcur[b], 1);
                stage[slot] = ((d & (VPB - 1)) << 17) | src[i];
                binid[slot] = (unsigned char)b;
            }
        }
    }
    __syncthreads();

    // pass 3: coalesced write-out per bucket run
    for (int j = tid; j < chunk; j += blockDim.x) {
        int b = binid[j];
        int idx = gbase[b] + (j - offs[b]);
        if (idx < CAP) binned[b * CAP + idx] = stage[j];
    }
}

// One block per bucket: LDS histogram (-> deg/cnt/dinv), PADDED LDS scan
// (segments rounded up to multiples of 8, filler = sentinel node n), one atomic
// for the bucket CSR base, LDS scatter, coalesced col write-out.
// Also emits xw[nid] = x[nid]*dinv[nid].
__global__ void k_bucket(const int* __restrict__ binned, const int* __restrict__ bktCur,
                         int* __restrict__ gtotal, int* __restrict__ rowstart,
                         int* __restrict__ cntG, float* __restrict__ dinv,
                         int* __restrict__ col, const float* __restrict__ x,
                         float* __restrict__ xw, int n) {
    __shared__ int buf[VPB];
    __shared__ int cur[VPB];
    __shared__ int colStage[CAP];
    __shared__ int sBase;
    const int tid = threadIdx.x;                 // blockDim = VPB
    const int b = blockIdx.x;
    const int nodeBase = b << VSH;
    const int count = min(bktCur[b], CAP);
    const int* bb = binned + b * CAP;

    buf[tid] = 0;
    __syncthreads();
    for (int i = tid; i < count; i += VPB)
        atomicAdd(&buf[bb[i] >> 17], 1);
    __syncthreads();
    int v = buf[tid];                            // real degree
    int vpad = (v + 7) & ~7;                     // padded segment length
    buf[tid] = vpad;
    __syncthreads();
    for (int off = 1; off < VPB; off <<= 1) {
        int t = (tid >= off) ? buf[tid - off] : 0;
        __syncthreads();
        buf[tid] += t;
        __syncthreads();
    }
    int excl = buf[tid] - vpad;
    if (tid == 0) sBase = atomicAdd(gtotal, buf[VPB - 1]);
    __syncthreads();
    int totalPad = buf[VPB - 1];
    int base = sBase;
    int nid = nodeBase + tid;
    if (nid < n) {
        float dv = rsqrtf((float)v + 1.0f);
        rowstart[nid] = base + excl;
        cntG[nid] = v;
        dinv[nid] = dv;
        const float* xr = x + (size_t)nid * 3;
        float* xo = xw + (size_t)nid * 3;
        xo[0] = xr[0] * dv;
        xo[1] = xr[1] * dv;
        xo[2] = xr[2] * dv;
    }
    cur[tid] = excl;
    for (int j = tid; j < totalPad && j < CAP; j += VPB) colStage[j] = n;
    __syncthreads();
    for (int i = tid; i < count; i += VPB) {
        int p = bb[i];
        int slot = atomicAdd(&cur[p >> 17], 1);
        colStage[slot] = p & 0x1FFFF;
    }
    __syncthreads();
    for (int j = tid; j < totalPad && j < CAP; j += VPB)
        col[base + j] = colStage[j];
}

// ---------------- layers ----------------

// FUSED layer-0 aggregation + layer-0/1 GEMM:
//   phase A : xa[r] = dn*(xw[r] + sum_s xw[s])          (3-dim gather, L2-hot)
//   phase A2: h0[r][c] = relu(xa[r]·W0[:,c] + b0[c])    -> hT (LDS, fp32)
//   phase B : t1s = (h0 @ W1) * dinv, bf16 out
__global__ __launch_bounds__(256) void k_l01(const float* __restrict__ xw,
        const float* __restrict__ dinv, const int* __restrict__ rowstart,
        const int* __restrict__ cnt, const int* __restrict__ col,
        const float* __restrict__ W0, const float* __restrict__ b0,
        const float* __restrict__ W1, unsigned short* __restrict__ t, int n) {
    __shared__ float hT[64 * GSTR];      // [k][node], stride GSTR
    __shared__ float Ws[64 * 64];        // [k][j] = W1
    __shared__ float W0s[3 * 64];
    __shared__ float b0s[64];
    __shared__ float xas[GN * 3];
    const int tid = threadIdx.x;
    const int n0 = blockIdx.x * GN;

    // stage W1 / W0 / b0
    {
        const float4* W4 = (const float4*)W1;
        float4* Ws4 = (float4*)Ws;
        for (int i = tid; i < 1024; i += 256) Ws4[i] = W4[i];
    }
    if (tid < 64) b0s[tid] = b0[tid];
    if (tid >= 64 && tid < 256) { int i = tid - 64; W0s[i] = W0[i]; }
    if (tid < 3 * 64 - 192) W0s[192 + tid] = W0[192 + tid];   // covers 192..191 (none) — W0 fully covered above? 192 elems: tid 64..255 -> 0..191 ✓

    // phase A: 64 groups x 4 lanes; 2 nodes per group; 3-dim gather from xw
    {
        const int gl  = tid & 3;
        const int grp = tid >> 2;         // 0..63
#pragma unroll
        for (int i = 0; i < 2; ++i) {
            int r = grp * 2 + i;          // local node 0..127
            int node = n0 + r;
            float res = 0.f;
            if (node < n) {
                float dn = dinv[node];
                float a = (gl < 3) ? xw[(size_t)node * 3 + gl] : 0.f;
                int s0 = rowstart[node];
                int cpad = (cnt[node] + 7) & ~7;
                for (int base = 0; base < cpad; base += 4) {
                    int myidx = col[s0 + base + gl];
#pragma unroll
                    for (int j = 0; j < 4; ++j) {
                        int s = __shfl(myidx, j, 4);
                        if (gl < 3) a += xw[(size_t)s * 3 + gl];  // sentinel = zeros
                    }
                }
                res = a * dn;
            }
            if (gl < 3) xas[r * 3 + gl] = res;
        }
    }
    __syncthreads();

    // phase A2: h0 tile transposed into hT
    for (int p = 0; p < 8; ++p) {
        int idx = p * 256 + tid;          // 0..2047
        int r = idx >> 4;                 // local node 0..127
        int c4 = idx & 15;
        float x0 = xas[r * 3 + 0], x1 = xas[r * 3 + 1], x2 = xas[r * 3 + 2];
#pragma unroll
        for (int q = 0; q < 4; ++q) {
            int c = c4 * 4 + q;
            float h = fmaf(x0, W0s[c], fmaf(x1, W0s[64 + c], fmaf(x2, W0s[128 + c], b0s[c])));
            hT[c * GSTR + r] = fmaxf(h, 0.f);
        }
    }
    __syncthreads();

    // phase B: 4 waves; thread tile = 4 nodes x 8 cols
    const int lane = tid & 63;
    const int wave = tid >> 6;           // 0..3
    const int ng = lane >> 3;            // 0..7
    const int cg = lane & 7;             // 0..7
    const int nodeLoc = wave * 32 + ng * 4;

    float4 acc[4][2];
#pragma unroll
    for (int i = 0; i < 4; ++i) {
        acc[i][0] = make_float4(0.f, 0.f, 0.f, 0.f);
        acc[i][1] = make_float4(0.f, 0.f, 0.f, 0.f);
    }

#pragma unroll 4
    for (int k = 0; k < 64; ++k) {
        float4 a = *(const float4*)(hT + k * GSTR + nodeLoc);
        const float4* bp = (const float4*)(Ws + k * 64 + cg * 8);
        float4 b0v = bp[0], b1v = bp[1];
        const float av[4] = { a.x, a.y, a.z, a.w };
#pragma unroll
        for (int i = 0; i < 4; ++i) {
            acc[i][0].x = fmaf(av[i], b0v.x, acc[i][0].x);
            acc[i][0].y = fmaf(av[i], b0v.y, acc[i][0].y);
            acc[i][0].z = fmaf(av[i], b0v.z, acc[i][0].z);
            acc[i][0].w = fmaf(av[i], b0v.w, acc[i][0].w);
            acc[i][1].x = fmaf(av[i], b1v.x, acc[i][1].x);
            acc[i][1].y = fmaf(av[i], b1v.y, acc[i][1].y);
            acc[i][1].z = fmaf(av[i], b1v.z, acc[i][1].z);
            acc[i][1].w = fmaf(av[i], b1v.w, acc[i][1].w);
        }
    }

#pragma unroll
    for (int i = 0; i < 4; ++i) {
        int row = n0 + nodeLoc + i;
        if (row < n) {
            float dv = dinv[row];
            uint4 pk;
            pk.x = packbf2(acc[i][0].x * dv, acc[i][0].y * dv);
            pk.y = packbf2(acc[i][0].z * dv, acc[i][0].w * dv);
            pk.z = packbf2(acc[i][1].x * dv, acc[i][1].y * dv);
            pk.w = packbf2(acc[i][1].z * dv, acc[i][1].w * dv);
            *(uint4*)(t + (size_t)row * 64 + cg * 8) = pk;
        }
    }
}

// FUSED layer-1 aggregation + layer-2 GEMM (GN=128 nodes/block, 512 threads):
//   h2[r][j] = relu(b1[j] + dn*(t1s[r][j] + sum_s t1s[s][j]))   (phase A -> hP bf16x2)
//   t2s = (h2 @ W2) * dinv, bf16 out                            (phase B)
// LDS ~33KB, 8 waves/block -> high occupancy during the gather phase.
__global__ __launch_bounds__(512) void k_aggemm(const unsigned short* __restrict__ t,
        const float* __restrict__ dinv, const int* __restrict__ rowstart,
        const int* __restrict__ cnt, const int* __restrict__ col,
        const float* __restrict__ b, const float* __restrict__ W,
        unsigned short* __restrict__ out, int n) {
    __shared__ unsigned hP[32 * PSTR];   // [channel pair][node], packed bf16x2
    __shared__ float Ws[64 * 64];        // [k][j] = W2
    const int tid = threadIdx.x;
    const int n0 = blockIdx.x * GN;

    // stage W2
    {
        const float4* W4 = (const float4*)W;
        float4* Ws4 = (float4*)Ws;
        for (int i = tid; i < 1024; i += 512) Ws4[i] = W4[i];
    }

    // phase A: 64 groups x 8 lanes; 2 nodes per group; gather + relu + pack
    {
        const int gl  = tid & 7;          // lane in group (8 bf16 channels)
        const int grp = tid >> 3;         // 0..63
        const float4 bv0 = ((const float4*)b)[gl * 2];
        const float4 bv1 = ((const float4*)b)[gl * 2 + 1];
#pragma unroll
        for (int i = 0; i < 2; ++i) {
            int r = grp * 2 + i;          // local node 0..127
            int node = n0 + r;
            float h0 = 0.f, h1 = 0.f, h2 = 0.f, h3 = 0.f;
            float h4 = 0.f, h5 = 0.f, h6 = 0.f, h7 = 0.f;
            if (node < n) {
                float dn = dinv[node];
                uint4 tv = *(const uint4*)(t + (size_t)node * 64 + gl * 8);
                float a0 = bflo(tv.x), a1 = bfhi(tv.x), a2 = bflo(tv.y), a3 = bfhi(tv.y);
                float a4 = bflo(tv.z), a5 = bfhi(tv.z), a6 = bflo(tv.w), a7 = bfhi(tv.w);
                int s0 = rowstart[node];
                int cpad = (cnt[node] + 7) & ~7;
                for (int base = 0; base < cpad; base += 8) {
                    int myidx = col[s0 + base + gl];
#pragma unroll
                    for (int j = 0; j < 8; ++j) {
                        int s = __shfl(myidx, j, 8);
                        uint4 g = *(const uint4*)(t + (size_t)s * 64 + gl * 8);
                        a0 += bflo(g.x); a1 += bfhi(g.x);
                        a2 += bflo(g.y); a3 += bfhi(g.y);
                        a4 += bflo(g.z); a5 += bfhi(g.z);
                        a6 += bflo(g.w); a7 += bfhi(g.w);
                    }
                }
                h0 = fmaxf(fmaf(a0, dn, bv0.x), 0.f);
                h1 = fmaxf(fmaf(a1, dn, bv0.y), 0.f);
                h2 = fmaxf(fmaf(a2, dn, bv0.z), 0.f);
                h3 = fmaxf(fmaf(a3, dn, bv0.w), 0.f);
                h4 = fmaxf(fmaf(a4, dn, bv1.x), 0.f);
                h5 = fmaxf(fmaf(a5, dn, bv1.y), 0.f);
                h6 = fmaxf(fmaf(a6, dn, bv1.z), 0.f);
                h7 = fmaxf(fmaf(a7, dn, bv1.w), 0.f);
            }
            int c2 = gl * 4;              // pair-row base
            hP[(c2 + 0) * PSTR + r] = packbf2(h0, h1);
            hP[(c2 + 1) * PSTR + r] = packbf2(h2, h3);
            hP[(c2 + 2) * PSTR + r] = packbf2(h4, h5);
            hP[(c2 + 3) * PSTR + r] = packbf2(h6, h7);
        }
    }
    __syncthreads();

    // phase B: 8 waves; thread tile = 4 nodes x 4 cols; 32 pair-iterations.
    const int lane = tid & 63;
    const int wave = tid >> 6;           // 0..7
    const int ng = lane >> 4;            // 0..3
    const int cg = lane & 15;            // 0..15
    const int nodeLoc = wave * 16 + ng * 4;

    float4 acc[4];
#pragma unroll
    for (int i = 0; i < 4; ++i) acc[i] = make_float4(0.f, 0.f, 0.f, 0.f);

#pragma unroll 4
    for (int kk = 0; kk < 32; ++kk) {
        uint4 ap = *(const uint4*)(hP + kk * PSTR + nodeLoc);   // 4 nodes' pairs
        float4 blo = *(const float4*)(Ws + (2 * kk) * 64 + cg * 4);
        float4 bhi = *(const float4*)(Ws + (2 * kk + 1) * 64 + cg * 4);
        const float alo[4] = { bflo(ap.x), bflo(ap.y), bflo(ap.z), bflo(ap.w) };
        const float ahi[4] = { bfhi(ap.x), bfhi(ap.y), bfhi(ap.z), bfhi(ap.w) };
#pragma unroll
        for (int i = 0; i < 4; ++i) {
            acc[i].x = fmaf(alo[i], blo.x, acc[i].x);
            acc[i].y = fmaf(alo[i], blo.y, acc[i].y);
            acc[i].z = fmaf(alo[i], blo.z, acc[i].z);
            acc[i].w = fmaf(alo[i], blo.w, acc[i].w);
            acc[i].x = fmaf(ahi[i], bhi.x, acc[i].x);
            acc[i].y = fmaf(ahi[i], bhi.y, acc[i].y);
            acc[i].z = fmaf(ahi[i], bhi.z, acc[i].z);
            acc[i].w = fmaf(ahi[i], bhi.w, acc[i].w);
        }
    }

#pragma unroll
    for (int i = 0; i < 4; ++i) {
        int row = n0 + nodeLoc + i;
        if (row < n) {
            float dv = dinv[row];
            uint2 pk;
            pk.x = packbf2(acc[i].x * dv, acc[i].y * dv);
            pk.y = packbf2(acc[i].z * dv, acc[i].w * dv);
            *(uint2*)(out + (size_t)row * 64 + cg * 4) = pk;
        }
    }
}

// Final layer fused with output head:
// h3[j] = relu( b2[j] + dn*(ts[n][j] + sum ts[s][j]) ); out[n] = sigmoid(h3·Wo + bo)
__global__ void k_agg_out(const unsigned short* __restrict__ t, const float* __restrict__ dinv,
                          const int* __restrict__ rowstart, const int* __restrict__ cnt,
                          const int* __restrict__ col,
                          const float* __restrict__ b, const float* __restrict__ Wo,
                          const float* __restrict__ bo, float* __restrict__ out, int n) {
    const int gl  = threadIdx.x & 7;
    const int grp = threadIdx.x >> 3;
    const int gpb = blockDim.x >> 3;
    const float4 bv0 = ((const float4*)b)[gl * 2];
    const float4 bv1 = ((const float4*)b)[gl * 2 + 1];
    const float4 wv0 = ((const float4*)Wo)[gl * 2];
    const float4 wv1 = ((const float4*)Wo)[gl * 2 + 1];
    const float bo0 = bo[0];
    for (int node = blockIdx.x * gpb + grp; node < n; node += gpb * gridDim.x) {
        float dn = dinv[node];
        uint4 tv = *(const uint4*)(t + (size_t)node * 64 + gl * 8);
        float a0 = bflo(tv.x), a1 = bfhi(tv.x), a2 = bflo(tv.y), a3 = bfhi(tv.y);
        float a4 = bflo(tv.z), a5 = bfhi(tv.z), a6 = bflo(tv.w), a7 = bfhi(tv.w);
        int s0 = rowstart[node];
        int cpad = (cnt[node] + 7) & ~7;
        for (int base = 0; base < cpad; base += 8) {
            int myidx = col[s0 + base + gl];
#pragma unroll
            for (int j = 0; j < 8; ++j) {
                int s = __shfl(myidx, j, 8);
                uint4 g = *(const uint4*)(t + (size_t)s * 64 + gl * 8);
                a0 += bflo(g.x); a1 += bfhi(g.x);
                a2 += bflo(g.y); a3 += bfhi(g.y);
                a4 += bflo(g.z); a5 += bfhi(g.z);
                a6 += bflo(g.w); a7 += bfhi(g.w);
            }
        }
        float v = fmaxf(fmaf(a0, dn, bv0.x), 0.f) * wv0.x
                + fmaxf(fmaf(a1, dn, bv0.y), 0.f) * wv0.y
                + fmaxf(fmaf(a2, dn, bv0.z), 0.f) * wv0.z
                + fmaxf(fmaf(a3, dn, bv0.w), 0.f) * wv0.w
                + fmaxf(fmaf(a4, dn, bv1.x), 0.f) * wv1.x
                + fmaxf(fmaf(a5, dn, bv1.y), 0.f) * wv1.y
                + fmaxf(fmaf(a6, dn, bv1.z), 0.f) * wv1.z
                + fmaxf(fmaf(a7, dn, bv1.w), 0.f) * wv1.w;
#pragma unroll
        for (int off = 4; off > 0; off >>= 1) v += __shfl_xor(v, off, 8);
        if (gl == 0) out[node] = 1.0f / (1.0f + expf(-(v + bo0)));
    }
}

// ---------------- launch ----------------

extern "C" void kernel_launch(void* const* d_in, const int* in_sizes, int n_in,
                              void* d_out, int out_size, void* d_ws, size_t ws_size,
                              hipStream_t stream) {
    const float* x  = (const float*)d_in[0];
    const int*   ei = (const int*)d_in[1];
    const float* W0 = (const float*)d_in[2];
    const float* b0 = (const float*)d_in[3];
    const float* W1 = (const float*)d_in[4];
    const float* b1 = (const float*)d_in[5];
    const float* W2 = (const float*)d_in[6];
    const float* b2 = (const float*)d_in[7];
    const float* Wo = (const float*)d_in[8];
    const float* bo = (const float*)d_in[9];
    float* out = (float*)d_out;

    const int N = in_sizes[0] / 3;
    const int E = in_sizes[1] / 2;
    const int* src = ei;
    const int* dst = ei + E;
    const int nb = (N + VPB - 1) >> VSH;

    char* w = (char*)d_ws;
    size_t off = 0;
    auto take = [&](size_t bytes) -> void* {
        void* p = w + off;
        off = (off + bytes + 255) & ~(size_t)255;
        return p;
    };
    float* dinv     = (float*)take((size_t)N * 4);
    int*   cnt      = (int*)take((size_t)N * 4);
    int*   rowstart = (int*)take((size_t)N * 4);
    int*   gtotal   = (int*)take(4);
    int*   bktCur   = (int*)take(MAXB * 4);
    float* xw       = (float*)take((size_t)(N + 1) * 3 * 4);      // +sentinel row
    int*   col      = (int*)take(((size_t)E + 8 * (size_t)N) * 4); // padded CSR
    unsigned short* A  = (unsigned short*)take((size_t)(N + 1) * 64 * 2); // bf16 t1s (+sentinel)
    unsigned short* A2 = (unsigned short*)take((size_t)(N + 1) * 64 * 2); // bf16 t2s (+sentinel)
    int*   binned   = (int*)take((size_t)MAXB * CAP * 4);
    (void)ws_size; (void)n_in; (void)out_size;

    const int TB = 256;
    // graph prep: bin -> per-bucket padded CSR build (also emits dinv + xw)
    k_zero  <<<1, 256, 0, stream>>>(bktCur, gtotal, A + (size_t)N * 64,
                                    A2 + (size_t)N * 64, xw + (size_t)N * 3);
    k_bin   <<<(E + BINCH - 1) / BINCH, TB, 0, stream>>>(src, dst, bktCur, binned, E, nb);
    k_bucket<<<nb, VPB, 0, stream>>>(binned, bktCur, gtotal, rowstart, cnt, dinv, col, x, xw, N);

    // FUSED layer-0 agg + layer-0/1 GEMM -> bf16 A
    k_l01   <<<(N + GN - 1) / GN, 256, 0, stream>>>(xw, dinv, rowstart, cnt, col,
                                                    W0, b0, W1, A, N);
    // FUSED layer-1 aggregation + layer-2 GEMM -> bf16 A2 (h2 never materialized)
    k_aggemm<<<(N + GN - 1) / GN, 512, 0, stream>>>(A, dinv, rowstart, cnt, col,
                                                    b1, W2, A2, N);
    // layer-2 aggregation + output head
    k_agg_out<<<2048, TB, 0, stream>>>(A2, dinv, rowstart, cnt, col, b2, Wo, bo, out, N);
}

// Round 17
// 156.199 us; speedup vs baseline: 1.0326x; 1.0326x over previous
//
#include <hip/hip_runtime.h>
#include <math.h>

// Graph constants for this problem size (N=100000, E=1600000).
#define VSH   9                  // nodes per bucket = 512
#define VPB   512
#define MAXB  256                // max buckets (N <= 131072)
#define CAP   12288              // per-bucket edge capacity (padded)
#define BINCH 8192               // edges per k_bin block

// GEMM tiling
#define GN    128                // nodes per block (k_l01)
#define GSTR  132                // hT row stride in floats (16B-aligned; 2-way banks)
#define GN2   64                 // nodes per block (k_aggemm)
#define PSTR  68                 // hP pair-row stride in unsigned (16B-aligned)

// ---------------- bf16 helpers (RNE) ----------------
__device__ __forceinline__ float bflo(unsigned u) { return __uint_as_float(u << 16); }
__device__ __forceinline__ float bfhi(unsigned u) { return __uint_as_float(u & 0xFFFF0000u); }
__device__ __forceinline__ unsigned packbf2(float a, float b) {
    unsigned ua = __float_as_uint(a);
    unsigned ub = __float_as_uint(b);
    ua += 0x7FFFu + ((ua >> 16) & 1u);   // round-to-nearest-even
    ub += 0x7FFFu + ((ub >> 16) & 1u);
    return (ua >> 16) | (ub & 0xFFFF0000u);
}

// ---------------- graph prep ----------------

// zero counters + the sentinel rows (node id == n) of A, A2 and xw
__global__ void k_zero(int* __restrict__ bktCur, int* __restrict__ gtotal,
                       unsigned short* __restrict__ tz, unsigned short* __restrict__ tz2,
                       float* __restrict__ xwz) {
    int i = threadIdx.x;
    if (i < MAXB) bktCur[i] = 0;
    if (i == 0) *gtotal = 0;
    if (i < 64) { tz[i] = 0; tz2[i] = 0; }
    if (i < 3) xwz[i] = 0.f;
}

// Bin edges by dst bucket. Per block: LDS histogram -> per-bucket global
// reservation -> LDS stage ordered by bucket -> coalesced write-out.
__global__ void k_bin(const int* __restrict__ src, const int* __restrict__ dst,
                      int* __restrict__ bktCur, int* __restrict__ binned,
                      int e, int nb) {
    __shared__ int hist[MAXB];
    __shared__ int offs[MAXB];
    __shared__ int gbase[MAXB];
    __shared__ int lcur[MAXB];
    __shared__ int stage[BINCH];
    __shared__ unsigned char binid[BINCH];
    const int tid = threadIdx.x;
    const int blockStart = blockIdx.x * BINCH;
    const int chunk = min(BINCH, e - blockStart);

    for (int b = tid; b < MAXB; b += blockDim.x) hist[b] = 0;
    __syncthreads();

    // pass 1: histogram
    for (int k = 0; k < BINCH / 1024; ++k) {
        int i0 = blockStart + k * 1024 + tid * 4;
        if (i0 + 3 < e) {
            int4 d4 = *(const int4*)(dst + i0);
            atomicAdd(&hist[d4.x >> VSH], 1);
            atomicAdd(&hist[d4.y >> VSH], 1);
            atomicAdd(&hist[d4.z >> VSH], 1);
            atomicAdd(&hist[d4.w >> VSH], 1);
        } else {
            for (int i = i0; i < e && i < i0 + 4; ++i)
                atomicAdd(&hist[dst[i] >> VSH], 1);
        }
    }
    __syncthreads();

    if (tid == 0) {
        int run = 0;
        for (int b = 0; b < nb; ++b) { offs[b] = run; run += hist[b]; }
    }
    __syncthreads();
    if (tid < nb) {
        gbase[tid] = (hist[tid] > 0) ? atomicAdd(&bktCur[tid], hist[tid]) : 0;
        lcur[tid] = offs[tid];
    }
    __syncthreads();

    // pass 2: stage ordered by bucket (re-read edges, L2-hot)
    for (int k = 0; k < BINCH / 1024; ++k) {
        int i0 = blockStart + k * 1024 + tid * 4;
        if (i0 + 3 < e) {
            int4 s4 = *(const int4*)(src + i0);
            int4 d4 = *(const int4*)(dst + i0);
            int bs[4] = { d4.x >> VSH, d4.y >> VSH, d4.z >> VSH, d4.w >> VSH };
            int pk[4] = { ((d4.x & (VPB - 1)) << 17) | s4.x,
                          ((d4.y & (VPB - 1)) << 17) | s4.y,
                          ((d4.z & (VPB - 1)) << 17) | s4.z,
                          ((d4.w & (VPB - 1)) << 17) | s4.w };
#pragma unroll
            for (int q = 0; q < 4; ++q) {
                int slot = atomicAdd(&lcur[bs[q]], 1);
                stage[slot] = pk[q];
                binid[slot] = (unsigned char)bs[q];
            }
        } else {
            for (int i = i0; i < e && i < i0 + 4; ++i) {
                int d = dst[i], b = d >> VSH;
                int slot = atomicAdd(&lcur[b], 1);
                stage[slot] = ((d & (VPB - 1)) << 17) | src[i];
                binid[slot] = (unsigned char)b;
            }
        }
    }
    __syncthreads();

    // pass 3: coalesced write-out per bucket run
    for (int j = tid; j < chunk; j += blockDim.x) {
        int b = binid[j];
        int idx = gbase[b] + (j - offs[b]);
        if (idx < CAP) binned[b * CAP + idx] = stage[j];
    }
}

// One block per bucket: LDS histogram (-> deg/cnt/dinv), PADDED LDS scan
// (segments rounded up to multiples of 8, filler = sentinel node n), one atomic
// for the bucket CSR base, LDS scatter, coalesced col write-out.
// Also emits xw[nid] = x[nid]*dinv[nid].
__global__ void k_bucket(const int* __restrict__ binned, const int* __restrict__ bktCur,
                         int* __restrict__ gtotal, int* __restrict__ rowstart,
                         int* __restrict__ cntG, float* __restrict__ dinv,
                         int* __restrict__ col, const float* __restrict__ x,
                         float* __restrict__ xw, int n) {
    __shared__ int buf[VPB];
    __shared__ int cur[VPB];
    __shared__ int colStage[CAP];
    __shared__ int sBase;
    const int tid = threadIdx.x;                 // blockDim = VPB
    const int b = blockIdx.x;
    const int nodeBase = b << VSH;
    const int count = min(bktCur[b], CAP);
    const int* bb = binned + b * CAP;

    buf[tid] = 0;
    __syncthreads();
    for (int i = tid; i < count; i += VPB)
        atomicAdd(&buf[bb[i] >> 17], 1);
    __syncthreads();
    int v = buf[tid];                            // real degree
    int vpad = (v + 7) & ~7;                     // padded segment length
    buf[tid] = vpad;
    __syncthreads();
    for (int off = 1; off < VPB; off <<= 1) {
        int t = (tid >= off) ? buf[tid - off] : 0;
        __syncthreads();
        buf[tid] += t;
        __syncthreads();
    }
    int excl = buf[tid] - vpad;
    if (tid == 0) sBase = atomicAdd(gtotal, buf[VPB - 1]);
    __syncthreads();
    int totalPad = buf[VPB - 1];
    int base = sBase;
    int nid = nodeBase + tid;
    if (nid < n) {
        float dv = rsqrtf((float)v + 1.0f);
        rowstart[nid] = base + excl;
        cntG[nid] = v;
        dinv[nid] = dv;
        const float* xr = x + (size_t)nid * 3;
        float* xo = xw + (size_t)nid * 3;
        xo[0] = xr[0] * dv;
        xo[1] = xr[1] * dv;
        xo[2] = xr[2] * dv;
    }
    cur[tid] = excl;
    for (int j = tid; j < totalPad && j < CAP; j += VPB) colStage[j] = n;
    __syncthreads();
    for (int i = tid; i < count; i += VPB) {
        int p = bb[i];
        int slot = atomicAdd(&cur[p >> 17], 1);
        colStage[slot] = p & 0x1FFFF;
    }
    __syncthreads();
    for (int j = tid; j < totalPad && j < CAP; j += VPB)
        col[base + j] = colStage[j];
}

// ---------------- layers ----------------

// FUSED layer-0 aggregation + layer-0/1 GEMM:
//   phase A : xa[r] = dn*(xw[r] + sum_s xw[s])          (3-dim gather, L2-hot)
//   phase A2: h0[r][c] = relu(xa[r]·W0[:,c] + b0[c])    -> hT (LDS, fp32)
//   phase B : t1s = (h0 @ W1) * dinv, bf16 out
__global__ __launch_bounds__(256) void k_l01(const float* __restrict__ xw,
        const float* __restrict__ dinv, const int* __restrict__ rowstart,
        const int* __restrict__ cnt, const int* __restrict__ col,
        const float* __restrict__ W0, const float* __restrict__ b0,
        const float* __restrict__ W1, unsigned short* __restrict__ t, int n) {
    __shared__ float hT[64 * GSTR];      // [k][node], stride GSTR
    __shared__ float Ws[64 * 64];        // [k][j] = W1
    __shared__ float W0s[3 * 64];
    __shared__ float b0s[64];
    __shared__ float xas[GN * 3];
    const int tid = threadIdx.x;
    const int n0 = blockIdx.x * GN;

    // stage W1 / W0 / b0
    {
        const float4* W4 = (const float4*)W1;
        float4* Ws4 = (float4*)Ws;
        for (int i = tid; i < 1024; i += 256) Ws4[i] = W4[i];
    }
    if (tid < 64) b0s[tid] = b0[tid];
    if (tid >= 64 && tid < 256) { int i = tid - 64; W0s[i] = W0[i]; }

    // phase A: 64 groups x 4 lanes; 2 nodes per group; 3-dim gather from xw
    {
        const int gl  = tid & 3;
        const int grp = tid >> 2;         // 0..63
#pragma unroll
        for (int i = 0; i < 2; ++i) {
            int r = grp * 2 + i;          // local node 0..127
            int node = n0 + r;
            float res = 0.f;
            if (node < n) {
                float dn = dinv[node];
                float a = (gl < 3) ? xw[(size_t)node * 3 + gl] : 0.f;
                int s0 = rowstart[node];
                int cpad = (cnt[node] + 7) & ~7;
                for (int base = 0; base < cpad; base += 4) {
                    int myidx = col[s0 + base + gl];
#pragma unroll
                    for (int j = 0; j < 4; ++j) {
                        int s = __shfl(myidx, j, 4);
                        if (gl < 3) a += xw[(size_t)s * 3 + gl];  // sentinel = zeros
                    }
                }
                res = a * dn;
            }
            if (gl < 3) xas[r * 3 + gl] = res;
        }
    }
    __syncthreads();

    // phase A2: h0 tile transposed into hT
    for (int p = 0; p < 8; ++p) {
        int idx = p * 256 + tid;          // 0..2047
        int r = idx >> 4;                 // local node 0..127
        int c4 = idx & 15;
        float x0 = xas[r * 3 + 0], x1 = xas[r * 3 + 1], x2 = xas[r * 3 + 2];
#pragma unroll
        for (int q = 0; q < 4; ++q) {
            int c = c4 * 4 + q;
            float h = fmaf(x0, W0s[c], fmaf(x1, W0s[64 + c], fmaf(x2, W0s[128 + c], b0s[c])));
            hT[c * GSTR + r] = fmaxf(h, 0.f);
        }
    }
    __syncthreads();

    // phase B: 4 waves; thread tile = 4 nodes x 8 cols
    const int lane = tid & 63;
    const int wave = tid >> 6;           // 0..3
    const int ng = lane >> 3;            // 0..7
    const int cg = lane & 7;             // 0..7
    const int nodeLoc = wave * 32 + ng * 4;

    float4 acc[4][2];
#pragma unroll
    for (int i = 0; i < 4; ++i) {
        acc[i][0] = make_float4(0.f, 0.f, 0.f, 0.f);
        acc[i][1] = make_float4(0.f, 0.f, 0.f, 0.f);
    }

#pragma unroll 4
    for (int k = 0; k < 64; ++k) {
        float4 a = *(const float4*)(hT + k * GSTR + nodeLoc);
        const float4* bp = (const float4*)(Ws + k * 64 + cg * 8);
        float4 b0v = bp[0], b1v = bp[1];
        const float av[4] = { a.x, a.y, a.z, a.w };
#pragma unroll
        for (int i = 0; i < 4; ++i) {
            acc[i][0].x = fmaf(av[i], b0v.x, acc[i][0].x);
            acc[i][0].y = fmaf(av[i], b0v.y, acc[i][0].y);
            acc[i][0].z = fmaf(av[i], b0v.z, acc[i][0].z);
            acc[i][0].w = fmaf(av[i], b0v.w, acc[i][0].w);
            acc[i][1].x = fmaf(av[i], b1v.x, acc[i][1].x);
            acc[i][1].y = fmaf(av[i], b1v.y, acc[i][1].y);
            acc[i][1].z = fmaf(av[i], b1v.z, acc[i][1].z);
            acc[i][1].w = fmaf(av[i], b1v.w, acc[i][1].w);
        }
    }

#pragma unroll
    for (int i = 0; i < 4; ++i) {
        int row = n0 + nodeLoc + i;
        if (row < n) {
            float dv = dinv[row];
            uint4 pk;
            pk.x = packbf2(acc[i][0].x * dv, acc[i][0].y * dv);
            pk.y = packbf2(acc[i][0].z * dv, acc[i][0].w * dv);
            pk.z = packbf2(acc[i][1].x * dv, acc[i][1].y * dv);
            pk.w = packbf2(acc[i][1].z * dv, acc[i][1].w * dv);
            *(uint4*)(t + (size_t)row * 64 + cg * 8) = pk;
        }
    }
}

// FUSED layer-1 aggregation + layer-2 GEMM (R15-proven config: GN2=64, 256 thr):
//   h2[r][j] = relu(b1[j] + dn*(t1s[r][j] + sum_s t1s[s][j]))   (phase A -> hP bf16x2)
//   t2s = (h2 @ W2) * dinv, bf16 out                            (phase B)
// LDS ~25KB -> 6 blocks/CU; grid 1563.
__global__ __launch_bounds__(256) void k_aggemm(const unsigned short* __restrict__ t,
        const float* __restrict__ dinv, const int* __restrict__ rowstart,
        const int* __restrict__ cnt, const int* __restrict__ col,
        const float* __restrict__ b, const float* __restrict__ W,
        unsigned short* __restrict__ out, int n) {
    __shared__ unsigned hP[32 * PSTR];   // [channel pair][node], packed bf16x2
    __shared__ float Ws[64 * 64];        // [k][j] = W2
    const int tid = threadIdx.x;
    const int n0 = blockIdx.x * GN2;

    // stage W2
    {
        const float4* W4 = (const float4*)W;
        float4* Ws4 = (float4*)Ws;
        for (int i = tid; i < 1024; i += 256) Ws4[i] = W4[i];
    }

    // phase A: 32 groups x 8 lanes; 2 nodes per group; gather + relu + pack
    {
        const int gl  = tid & 7;          // lane in group (8 bf16 channels)
        const int grp = tid >> 3;         // 0..31
        const float4 bv0 = ((const float4*)b)[gl * 2];
        const float4 bv1 = ((const float4*)b)[gl * 2 + 1];
#pragma unroll
        for (int i = 0; i < 2; ++i) {
            int r = grp * 2 + i;          // local node 0..63
            int node = n0 + r;
            float h0 = 0.f, h1 = 0.f, h2 = 0.f, h3 = 0.f;
            float h4 = 0.f, h5 = 0.f, h6 = 0.f, h7 = 0.f;
            if (node < n) {
                float dn = dinv[node];
                uint4 tv = *(const uint4*)(t + (size_t)node * 64 + gl * 8);
                float a0 = bflo(tv.x), a1 = bfhi(tv.x), a2 = bflo(tv.y), a3 = bfhi(tv.y);
                float a4 = bflo(tv.z), a5 = bfhi(tv.z), a6 = bflo(tv.w), a7 = bfhi(tv.w);
                int s0 = rowstart[node];
                int cpad = (cnt[node] + 7) & ~7;
                for (int base = 0; base < cpad; base += 8) {
                    int myidx = col[s0 + base + gl];
#pragma unroll
                    for (int j = 0; j < 8; ++j) {
                        int s = __shfl(myidx, j, 8);
                        uint4 g = *(const uint4*)(t + (size_t)s * 64 + gl * 8);
                        a0 += bflo(g.x); a1 += bfhi(g.x);
                        a2 += bflo(g.y); a3 += bfhi(g.y);
                        a4 += bflo(g.z); a5 += bfhi(g.z);
                        a6 += bflo(g.w); a7 += bfhi(g.w);
                    }
                }
                h0 = fmaxf(fmaf(a0, dn, bv0.x), 0.f);
                h1 = fmaxf(fmaf(a1, dn, bv0.y), 0.f);
                h2 = fmaxf(fmaf(a2, dn, bv0.z), 0.f);
                h3 = fmaxf(fmaf(a3, dn, bv0.w), 0.f);
                h4 = fmaxf(fmaf(a4, dn, bv1.x), 0.f);
                h5 = fmaxf(fmaf(a5, dn, bv1.y), 0.f);
                h6 = fmaxf(fmaf(a6, dn, bv1.z), 0.f);
                h7 = fmaxf(fmaf(a7, dn, bv1.w), 0.f);
            }
            int c2 = gl * 4;              // pair-row base (channels 2c2, 2c2+1)
            hP[(c2 + 0) * PSTR + r] = packbf2(h0, h1);
            hP[(c2 + 1) * PSTR + r] = packbf2(h2, h3);
            hP[(c2 + 2) * PSTR + r] = packbf2(h4, h5);
            hP[(c2 + 3) * PSTR + r] = packbf2(h6, h7);
        }
    }
    __syncthreads();

    // phase B: 4 waves; thread tile = 4 nodes x 4 cols; 32 pair-iterations.
    const int lane = tid & 63;
    const int wave = tid >> 6;           // 0..3
    const int ng = lane >> 4;            // 0..3
    const int cg = lane & 15;            // 0..15
    const int nodeLoc = wave * 16 + ng * 4;

    float4 acc[4];
#pragma unroll
    for (int i = 0; i < 4; ++i) acc[i] = make_float4(0.f, 0.f, 0.f, 0.f);

#pragma unroll 4
    for (int kk = 0; kk < 32; ++kk) {
        uint4 ap = *(const uint4*)(hP + kk * PSTR + nodeLoc);   // 4 nodes' pairs
        float4 blo = *(const float4*)(Ws + (2 * kk) * 64 + cg * 4);
        float4 bhi = *(const float4*)(Ws + (2 * kk + 1) * 64 + cg * 4);
        const float alo[4] = { bflo(ap.x), bflo(ap.y), bflo(ap.z), bflo(ap.w) };
        const float ahi[4] = { bfhi(ap.x), bfhi(ap.y), bfhi(ap.z), bfhi(ap.w) };
#pragma unroll
        for (int i = 0; i < 4; ++i) {
            acc[i].x = fmaf(alo[i], blo.x, acc[i].x);
            acc[i].y = fmaf(alo[i], blo.y, acc[i].y);
            acc[i].z = fmaf(alo[i], blo.z, acc[i].z);
            acc[i].w = fmaf(alo[i], blo.w, acc[i].w);
            acc[i].x = fmaf(ahi[i], bhi.x, acc[i].x);
            acc[i].y = fmaf(ahi[i], bhi.y, acc[i].y);
            acc[i].z = fmaf(ahi[i], bhi.z, acc[i].z);
            acc[i].w = fmaf(ahi[i], bhi.w, acc[i].w);
        }
    }

#pragma unroll
    for (int i = 0; i < 4; ++i) {
        int row = n0 + nodeLoc + i;
        if (row < n) {
            float dv = dinv[row];
            uint2 pk;
            pk.x = packbf2(acc[i].x * dv, acc[i].y * dv);
            pk.y = packbf2(acc[i].z * dv, acc[i].w * dv);
            *(uint2*)(out + (size_t)row * 64 + cg * 4) = pk;
        }
    }
}

// Final layer fused with output head:
// h3[j] = relu( b2[j] + dn*(ts[n][j] + sum ts[s][j]) ); out[n] = sigmoid(h3·Wo + bo)
__global__ void k_agg_out(const unsigned short* __restrict__ t, const float* __restrict__ dinv,
                          const int* __restrict__ rowstart, const int* __restrict__ cnt,
                          const int* __restrict__ col,
                          const float* __restrict__ b, const float* __restrict__ Wo,
                          const float* __restrict__ bo, float* __restrict__ out, int n) {
    const int gl  = threadIdx.x & 7;
    const int grp = threadIdx.x >> 3;
    const int gpb = blockDim.x >> 3;
    const float4 bv0 = ((const float4*)b)[gl * 2];
    const float4 bv1 = ((const float4*)b)[gl * 2 + 1];
    const float4 wv0 = ((const float4*)Wo)[gl * 2];
    const float4 wv1 = ((const float4*)Wo)[gl * 2 + 1];
    const float bo0 = bo[0];
    for (int node = blockIdx.x * gpb + grp; node < n; node += gpb * gridDim.x) {
        float dn = dinv[node];
        uint4 tv = *(const uint4*)(t + (size_t)node * 64 + gl * 8);
        float a0 = bflo(tv.x), a1 = bfhi(tv.x), a2 = bflo(tv.y), a3 = bfhi(tv.y);
        float a4 = bflo(tv.z), a5 = bfhi(tv.z), a6 = bflo(tv.w), a7 = bfhi(tv.w);
        int s0 = rowstart[node];
        int cpad = (cnt[node] + 7) & ~7;
        for (int base = 0; base < cpad; base += 8) {
            int myidx = col[s0 + base + gl];
#pragma unroll
            for (int j = 0; j < 8; ++j) {
                int s = __shfl(myidx, j, 8);
                uint4 g = *(const uint4*)(t + (size_t)s * 64 + gl * 8);
                a0 += bflo(g.x); a1 += bfhi(g.x);
                a2 += bflo(g.y); a3 += bfhi(g.y);
                a4 += bflo(g.z); a5 += bfhi(g.z);
                a6 += bflo(g.w); a7 += bfhi(g.w);
            }
        }
        float v = fmaxf(fmaf(a0, dn, bv0.x), 0.f) * wv0.x
                + fmaxf(fmaf(a1, dn, bv0.y), 0.f) * wv0.y
                + fmaxf(fmaf(a2, dn, bv0.z), 0.f) * wv0.z
                + fmaxf(fmaf(a3, dn, bv0.w), 0.f) * wv0.w
                + fmaxf(fmaf(a4, dn, bv1.x), 0.f) * wv1.x
                + fmaxf(fmaf(a5, dn, bv1.y), 0.f) * wv1.y
                + fmaxf(fmaf(a6, dn, bv1.z), 0.f) * wv1.z
                + fmaxf(fmaf(a7, dn, bv1.w), 0.f) * wv1.w;
#pragma unroll
        for (int off = 4; off > 0; off >>= 1) v += __shfl_xor(v, off, 8);
        if (gl == 0) out[node] = 1.0f / (1.0f + expf(-(v + bo0)));
    }
}

// ---------------- launch ----------------

extern "C" void kernel_launch(void* const* d_in, const int* in_sizes, int n_in,
                              void* d_out, int out_size, void* d_ws, size_t ws_size,
                              hipStream_t stream) {
    const float* x  = (const float*)d_in[0];
    const int*   ei = (const int*)d_in[1];
    const float* W0 = (const float*)d_in[2];
    const float* b0 = (const float*)d_in[3];
    const float* W1 = (const float*)d_in[4];
    const float* b1 = (const float*)d_in[5];
    const float* W2 = (const float*)d_in[6];
    const float* b2 = (const float*)d_in[7];
    const float* Wo = (const float*)d_in[8];
    const float* bo = (const float*)d_in[9];
    float* out = (float*)d_out;

    const int N = in_sizes[0] / 3;
    const int E = in_sizes[1] / 2;
    const int* src = ei;
    const int* dst = ei + E;
    const int nb = (N + VPB - 1) >> VSH;

    char* w = (char*)d_ws;
    size_t off = 0;
    auto take = [&](size_t bytes) -> void* {
        void* p = w + off;
        off = (off + bytes + 255) & ~(size_t)255;
        return p;
    };
    float* dinv     = (float*)take((size_t)N * 4);
    int*   cnt      = (int*)take((size_t)N * 4);
    int*   rowstart = (int*)take((size_t)N * 4);
    int*   gtotal   = (int*)take(4);
    int*   bktCur   = (int*)take(MAXB * 4);
    float* xw       = (float*)take((size_t)(N + 1) * 3 * 4);      // +sentinel row
    int*   col      = (int*)take(((size_t)E + 8 * (size_t)N) * 4); // padded CSR
    unsigned short* A  = (unsigned short*)take((size_t)(N + 1) * 64 * 2); // bf16 t1s (+sentinel)
    unsigned short* A2 = (unsigned short*)take((size_t)(N + 1) * 64 * 2); // bf16 t2s (+sentinel)
    int*   binned   = (int*)take((size_t)MAXB * CAP * 4);
    (void)ws_size; (void)n_in; (void)out_size;

    const int TB = 256;
    // graph prep: bin -> per-bucket padded CSR build (also emits dinv + xw)
    k_zero  <<<1, 256, 0, stream>>>(bktCur, gtotal, A + (size_t)N * 64,
                                    A2 + (size_t)N * 64, xw + (size_t)N * 3);
    k_bin   <<<(E + BINCH - 1) / BINCH, TB, 0, stream>>>(src, dst, bktCur, binned, E, nb);
    k_bucket<<<nb, VPB, 0, stream>>>(binned, bktCur, gtotal, rowstart, cnt, dinv, col, x, xw, N);

    // FUSED layer-0 agg + layer-0/1 GEMM -> bf16 A
    k_l01   <<<(N + GN - 1) / GN, 256, 0, stream>>>(xw, dinv, rowstart, cnt, col,
                                                    W0, b0, W1, A, N);
    // FUSED layer-1 aggregation + layer-2 GEMM -> bf16 A2 (h2 never materialized)
    k_aggemm<<<(N + GN2 - 1) / GN2, 256, 0, stream>>>(A, dinv, rowstart, cnt, col,
                                                      b1, W2, A2, N);
    // layer-2 aggregation + output head
    k_agg_out<<<2048, TB, 0, stream>>>(A2, dinv, rowstart, cnt, col, b2, Wo, bo, out, N);
}

// Round 18
// 143.416 us; speedup vs baseline: 1.1246x; 1.0891x over previous
//
#include <hip/hip_runtime.h>
#include <math.h>

// Graph constants for this problem size (N=100000, E=1600000).
#define VSH   9                  // nodes per bucket = 512
#define VPB   512
#define MAXB  256                // max buckets (N <= 131072)
#define CAP   12288              // per-bucket edge capacity (padded)
#define BINCH 8192               // edges per k_bin block

// Fused agg+GEMM tiling (k_l01 and k_aggemm share this proven structure)
#define GN2   64                 // nodes per block
#define PSTR  68                 // hP pair-row stride in unsigned (16B-aligned)

// ---------------- bf16 helpers (RNE) ----------------
__device__ __forceinline__ float bflo(unsigned u) { return __uint_as_float(u << 16); }
__device__ __forceinline__ float bfhi(unsigned u) { return __uint_as_float(u & 0xFFFF0000u); }
__device__ __forceinline__ unsigned packbf2(float a, float b) {
    unsigned ua = __float_as_uint(a);
    unsigned ub = __float_as_uint(b);
    ua += 0x7FFFu + ((ua >> 16) & 1u);   // round-to-nearest-even
    ub += 0x7FFFu + ((ub >> 16) & 1u);
    return (ua >> 16) | (ub & 0xFFFF0000u);
}

// ---------------- graph prep ----------------

// zero counters + the sentinel rows (node id == n) of A, A2 and xw
__global__ void k_zero(int* __restrict__ bktCur, int* __restrict__ gtotal,
                       unsigned short* __restrict__ tz, unsigned short* __restrict__ tz2,
                       float* __restrict__ xwz) {
    int i = threadIdx.x;
    if (i < MAXB) bktCur[i] = 0;
    if (i == 0) *gtotal = 0;
    if (i < 64) { tz[i] = 0; tz2[i] = 0; }
    if (i < 3) xwz[i] = 0.f;
}

// Bin edges by dst bucket. Per block: LDS histogram -> per-bucket global
// reservation -> LDS stage ordered by bucket -> coalesced write-out.
__global__ void k_bin(const int* __restrict__ src, const int* __restrict__ dst,
                      int* __restrict__ bktCur, int* __restrict__ binned,
                      int e, int nb) {
    __shared__ int hist[MAXB];
    __shared__ int offs[MAXB];
    __shared__ int gbase[MAXB];
    __shared__ int lcur[MAXB];
    __shared__ int stage[BINCH];
    __shared__ unsigned char binid[BINCH];
    const int tid = threadIdx.x;
    const int blockStart = blockIdx.x * BINCH;
    const int chunk = min(BINCH, e - blockStart);

    for (int b = tid; b < MAXB; b += blockDim.x) hist[b] = 0;
    __syncthreads();

    // pass 1: histogram
    for (int k = 0; k < BINCH / 1024; ++k) {
        int i0 = blockStart + k * 1024 + tid * 4;
        if (i0 + 3 < e) {
            int4 d4 = *(const int4*)(dst + i0);
            atomicAdd(&hist[d4.x >> VSH], 1);
            atomicAdd(&hist[d4.y >> VSH], 1);
            atomicAdd(&hist[d4.z >> VSH], 1);
            atomicAdd(&hist[d4.w >> VSH], 1);
        } else {
            for (int i = i0; i < e && i < i0 + 4; ++i)
                atomicAdd(&hist[dst[i] >> VSH], 1);
        }
    }
    __syncthreads();

    if (tid == 0) {
        int run = 0;
        for (int b = 0; b < nb; ++b) { offs[b] = run; run += hist[b]; }
    }
    __syncthreads();
    if (tid < nb) {
        gbase[tid] = (hist[tid] > 0) ? atomicAdd(&bktCur[tid], hist[tid]) : 0;
        lcur[tid] = offs[tid];
    }
    __syncthreads();

    // pass 2: stage ordered by bucket (re-read edges, L2-hot)
    for (int k = 0; k < BINCH / 1024; ++k) {
        int i0 = blockStart + k * 1024 + tid * 4;
        if (i0 + 3 < e) {
            int4 s4 = *(const int4*)(src + i0);
            int4 d4 = *(const int4*)(dst + i0);
            int bs[4] = { d4.x >> VSH, d4.y >> VSH, d4.z >> VSH, d4.w >> VSH };
            int pk[4] = { ((d4.x & (VPB - 1)) << 17) | s4.x,
                          ((d4.y & (VPB - 1)) << 17) | s4.y,
                          ((d4.z & (VPB - 1)) << 17) | s4.z,
                          ((d4.w & (VPB - 1)) << 17) | s4.w };
#pragma unroll
            for (int q = 0; q < 4; ++q) {
                int slot = atomicAdd(&lcur[bs[q]], 1);
                stage[slot] = pk[q];
                binid[slot] = (unsigned char)bs[q];
            }
        } else {
            for (int i = i0; i < e && i < i0 + 4; ++i) {
                int d = dst[i], b = d >> VSH;
                int slot = atomicAdd(&lcur[b], 1);
                stage[slot] = ((d & (VPB - 1)) << 17) | src[i];
                binid[slot] = (unsigned char)b;
            }
        }
    }
    __syncthreads();

    // pass 3: coalesced write-out per bucket run
    for (int j = tid; j < chunk; j += blockDim.x) {
        int b = binid[j];
        int idx = gbase[b] + (j - offs[b]);
        if (idx < CAP) binned[b * CAP + idx] = stage[j];
    }
}

// One block per bucket: LDS histogram (-> deg/cnt/dinv), PADDED LDS scan
// (segments rounded up to multiples of 8, filler = sentinel node n), one atomic
// for the bucket CSR base, LDS scatter, coalesced col write-out.
// Also emits xw[nid] = x[nid]*dinv[nid].
__global__ void k_bucket(const int* __restrict__ binned, const int* __restrict__ bktCur,
                         int* __restrict__ gtotal, int* __restrict__ rowstart,
                         int* __restrict__ cntG, float* __restrict__ dinv,
                         int* __restrict__ col, const float* __restrict__ x,
                         float* __restrict__ xw, int n) {
    __shared__ int buf[VPB];
    __shared__ int cur[VPB];
    __shared__ int colStage[CAP];
    __shared__ int sBase;
    const int tid = threadIdx.x;                 // blockDim = VPB
    const int b = blockIdx.x;
    const int nodeBase = b << VSH;
    const int count = min(bktCur[b], CAP);
    const int* bb = binned + b * CAP;

    buf[tid] = 0;
    __syncthreads();
    for (int i = tid; i < count; i += VPB)
        atomicAdd(&buf[bb[i] >> 17], 1);
    __syncthreads();
    int v = buf[tid];                            // real degree
    int vpad = (v + 7) & ~7;                     // padded segment length
    buf[tid] = vpad;
    __syncthreads();
    for (int off = 1; off < VPB; off <<= 1) {
        int t = (tid >= off) ? buf[tid - off] : 0;
        __syncthreads();
        buf[tid] += t;
        __syncthreads();
    }
    int excl = buf[tid] - vpad;
    if (tid == 0) sBase = atomicAdd(gtotal, buf[VPB - 1]);
    __syncthreads();
    int totalPad = buf[VPB - 1];
    int base = sBase;
    int nid = nodeBase + tid;
    if (nid < n) {
        float dv = rsqrtf((float)v + 1.0f);
        rowstart[nid] = base + excl;
        cntG[nid] = v;
        dinv[nid] = dv;
        const float* xr = x + (size_t)nid * 3;
        float* xo = xw + (size_t)nid * 3;
        xo[0] = xr[0] * dv;
        xo[1] = xr[1] * dv;
        xo[2] = xr[2] * dv;
    }
    cur[tid] = excl;
    for (int j = tid; j < totalPad && j < CAP; j += VPB) colStage[j] = n;
    __syncthreads();
    for (int i = tid; i < count; i += VPB) {
        int p = bb[i];
        int slot = atomicAdd(&cur[p >> 17], 1);
        colStage[slot] = p & 0x1FFFF;
    }
    __syncthreads();
    for (int j = tid; j < totalPad && j < CAP; j += VPB)
        col[base + j] = colStage[j];
}

// ---------------- layers ----------------

// FUSED layer-0 aggregation + layer-0/1 GEMM (R15-proven structure: GN2=64, 256 thr):
//   phase A : xa[r] = dn*(xw[r] + sum_s xw[s])            (3-dim gather, L2-hot;
//             ONE node per 4-lane group -> no serial node loop)
//   phase A2: h0[r][c] = relu(xa[r]·W0[:,c] + b0[c])      -> hP (LDS, bf16x2)
//   phase B : t1s = (h0 @ W1) * dinv, bf16 out
// LDS ~27KB -> 5 blocks/CU; grid 1563 -> high occupancy for the gather phase.
__global__ __launch_bounds__(256) void k_l01(const float* __restrict__ xw,
        const float* __restrict__ dinv, const int* __restrict__ rowstart,
        const int* __restrict__ cnt, const int* __restrict__ col,
        const float* __restrict__ W0, const float* __restrict__ b0,
        const float* __restrict__ W1, unsigned short* __restrict__ t, int n) {
    __shared__ unsigned hP[32 * PSTR];   // [channel pair][node], packed bf16x2
    __shared__ float Ws[64 * 64];        // [k][j] = W1
    __shared__ float W0s[3 * 64];
    __shared__ float b0s[64];
    __shared__ float xas[GN2 * 3];
    const int tid = threadIdx.x;
    const int n0 = blockIdx.x * GN2;

    // stage W1 / W0 / b0
    {
        const float4* W4 = (const float4*)W1;
        float4* Ws4 = (float4*)Ws;
        for (int i = tid; i < 1024; i += 256) Ws4[i] = W4[i];
    }
    if (tid < 64) b0s[tid] = b0[tid];
    if (tid >= 64 && tid < 256) W0s[tid - 64] = W0[tid - 64];

    // phase A: 64 groups x 4 lanes; ONE node per group; 3-dim gather from xw
    {
        const int gl  = tid & 3;
        const int grp = tid >> 2;         // 0..63 = local node
        int node = n0 + grp;
        float res = 0.f;
        if (node < n) {
            float dn = dinv[node];
            float a = (gl < 3) ? xw[(size_t)node * 3 + gl] : 0.f;
            int s0 = rowstart[node];
            int cpad = (cnt[node] + 7) & ~7;
            for (int base = 0; base < cpad; base += 4) {
                int myidx = col[s0 + base + gl];
#pragma unroll
                for (int j = 0; j < 4; ++j) {
                    int s = __shfl(myidx, j, 4);
                    if (gl < 3) a += xw[(size_t)s * 3 + gl];  // sentinel = zeros
                }
            }
            res = a * dn;
        }
        if (gl < 3) xas[grp * 3 + gl] = res;
    }
    __syncthreads();

    // phase A2: h0 compute + pack into hP. 32 pair-rows x 64 nodes = 2048 entries.
    for (int p = 0; p < 8; ++p) {
        int idx = p * 256 + tid;          // 0..2047
        int r = idx & 63;                 // local node
        int c2 = idx >> 6;                // pair-row 0..31
        float x0 = xas[r * 3 + 0], x1 = xas[r * 3 + 1], x2 = xas[r * 3 + 2];
        int c = c2 * 2;
        float hlo = fmaf(x0, W0s[c],     fmaf(x1, W0s[64 + c],     fmaf(x2, W0s[128 + c],     b0s[c])));
        float hhi = fmaf(x0, W0s[c + 1], fmaf(x1, W0s[64 + c + 1], fmaf(x2, W0s[128 + c + 1], b0s[c + 1])));
        hP[c2 * PSTR + r] = packbf2(fmaxf(hlo, 0.f), fmaxf(hhi, 0.f));
    }
    __syncthreads();

    // phase B: 4 waves; thread tile = 4 nodes x 4 cols; 32 pair-iterations.
    const int lane = tid & 63;
    const int wave = tid >> 6;           // 0..3
    const int ng = lane >> 4;            // 0..3
    const int cg = lane & 15;            // 0..15
    const int nodeLoc = wave * 16 + ng * 4;

    float4 acc[4];
#pragma unroll
    for (int i = 0; i < 4; ++i) acc[i] = make_float4(0.f, 0.f, 0.f, 0.f);

#pragma unroll 4
    for (int kk = 0; kk < 32; ++kk) {
        uint4 ap = *(const uint4*)(hP + kk * PSTR + nodeLoc);   // 4 nodes' pairs
        float4 blo = *(const float4*)(Ws + (2 * kk) * 64 + cg * 4);
        float4 bhi = *(const float4*)(Ws + (2 * kk + 1) * 64 + cg * 4);
        const float alo[4] = { bflo(ap.x), bflo(ap.y), bflo(ap.z), bflo(ap.w) };
        const float ahi[4] = { bfhi(ap.x), bfhi(ap.y), bfhi(ap.z), bfhi(ap.w) };
#pragma unroll
        for (int i = 0; i < 4; ++i) {
            acc[i].x = fmaf(alo[i], blo.x, acc[i].x);
            acc[i].y = fmaf(alo[i], blo.y, acc[i].y);
            acc[i].z = fmaf(alo[i], blo.z, acc[i].z);
            acc[i].w = fmaf(alo[i], blo.w, acc[i].w);
            acc[i].x = fmaf(ahi[i], bhi.x, acc[i].x);
            acc[i].y = fmaf(ahi[i], bhi.y, acc[i].y);
            acc[i].z = fmaf(ahi[i], bhi.z, acc[i].z);
            acc[i].w = fmaf(ahi[i], bhi.w, acc[i].w);
        }
    }

#pragma unroll
    for (int i = 0; i < 4; ++i) {
        int row = n0 + nodeLoc + i;
        if (row < n) {
            float dv = dinv[row];
            uint2 pk;
            pk.x = packbf2(acc[i].x * dv, acc[i].y * dv);
            pk.y = packbf2(acc[i].z * dv, acc[i].w * dv);
            *(uint2*)(t + (size_t)row * 64 + cg * 4) = pk;
        }
    }
}

// FUSED layer-1 aggregation + layer-2 GEMM (R15-proven config: GN2=64, 256 thr):
//   h2[r][j] = relu(b1[j] + dn*(t1s[r][j] + sum_s t1s[s][j]))   (phase A -> hP bf16x2)
//   t2s = (h2 @ W2) * dinv, bf16 out                            (phase B)
__global__ __launch_bounds__(256) void k_aggemm(const unsigned short* __restrict__ t,
        const float* __restrict__ dinv, const int* __restrict__ rowstart,
        const int* __restrict__ cnt, const int* __restrict__ col,
        const float* __restrict__ b, const float* __restrict__ W,
        unsigned short* __restrict__ out, int n) {
    __shared__ unsigned hP[32 * PSTR];   // [channel pair][node], packed bf16x2
    __shared__ float Ws[64 * 64];        // [k][j] = W2
    const int tid = threadIdx.x;
    const int n0 = blockIdx.x * GN2;

    // stage W2
    {
        const float4* W4 = (const float4*)W;
        float4* Ws4 = (float4*)Ws;
        for (int i = tid; i < 1024; i += 256) Ws4[i] = W4[i];
    }

    // phase A: 32 groups x 8 lanes; 2 nodes per group; gather + relu + pack
    {
        const int gl  = tid & 7;          // lane in group (8 bf16 channels)
        const int grp = tid >> 3;         // 0..31
        const float4 bv0 = ((const float4*)b)[gl * 2];
        const float4 bv1 = ((const float4*)b)[gl * 2 + 1];
#pragma unroll
        for (int i = 0; i < 2; ++i) {
            int r = grp * 2 + i;          // local node 0..63
            int node = n0 + r;
            float h0 = 0.f, h1 = 0.f, h2 = 0.f, h3 = 0.f;
            float h4 = 0.f, h5 = 0.f, h6 = 0.f, h7 = 0.f;
            if (node < n) {
                float dn = dinv[node];
                uint4 tv = *(const uint4*)(t + (size_t)node * 64 + gl * 8);
                float a0 = bflo(tv.x), a1 = bfhi(tv.x), a2 = bflo(tv.y), a3 = bfhi(tv.y);
                float a4 = bflo(tv.z), a5 = bfhi(tv.z), a6 = bflo(tv.w), a7 = bfhi(tv.w);
                int s0 = rowstart[node];
                int cpad = (cnt[node] + 7) & ~7;
                for (int base = 0; base < cpad; base += 8) {
                    int myidx = col[s0 + base + gl];
#pragma unroll
                    for (int j = 0; j < 8; ++j) {
                        int s = __shfl(myidx, j, 8);
                        uint4 g = *(const uint4*)(t + (size_t)s * 64 + gl * 8);
                        a0 += bflo(g.x); a1 += bfhi(g.x);
                        a2 += bflo(g.y); a3 += bfhi(g.y);
                        a4 += bflo(g.z); a5 += bfhi(g.z);
                        a6 += bflo(g.w); a7 += bfhi(g.w);
                    }
                }
                h0 = fmaxf(fmaf(a0, dn, bv0.x), 0.f);
                h1 = fmaxf(fmaf(a1, dn, bv0.y), 0.f);
                h2 = fmaxf(fmaf(a2, dn, bv0.z), 0.f);
                h3 = fmaxf(fmaf(a3, dn, bv0.w), 0.f);
                h4 = fmaxf(fmaf(a4, dn, bv1.x), 0.f);
                h5 = fmaxf(fmaf(a5, dn, bv1.y), 0.f);
                h6 = fmaxf(fmaf(a6, dn, bv1.z), 0.f);
                h7 = fmaxf(fmaf(a7, dn, bv1.w), 0.f);
            }
            int c2 = gl * 4;              // pair-row base (channels 2c2, 2c2+1)
            hP[(c2 + 0) * PSTR + r] = packbf2(h0, h1);
            hP[(c2 + 1) * PSTR + r] = packbf2(h2, h3);
            hP[(c2 + 2) * PSTR + r] = packbf2(h4, h5);
            hP[(c2 + 3) * PSTR + r] = packbf2(h6, h7);
        }
    }
    __syncthreads();

    // phase B: 4 waves; thread tile = 4 nodes x 4 cols; 32 pair-iterations.
    const int lane = tid & 63;
    const int wave = tid >> 6;           // 0..3
    const int ng = lane >> 4;            // 0..3
    const int cg = lane & 15;            // 0..15
    const int nodeLoc = wave * 16 + ng * 4;

    float4 acc[4];
#pragma unroll
    for (int i = 0; i < 4; ++i) acc[i] = make_float4(0.f, 0.f, 0.f, 0.f);

#pragma unroll 4
    for (int kk = 0; kk < 32; ++kk) {
        uint4 ap = *(const uint4*)(hP + kk * PSTR + nodeLoc);   // 4 nodes' pairs
        float4 blo = *(const float4*)(Ws + (2 * kk) * 64 + cg * 4);
        float4 bhi = *(const float4*)(Ws + (2 * kk + 1) * 64 + cg * 4);
        const float alo[4] = { bflo(ap.x), bflo(ap.y), bflo(ap.z), bflo(ap.w) };
        const float ahi[4] = { bfhi(ap.x), bfhi(ap.y), bfhi(ap.z), bfhi(ap.w) };
#pragma unroll
        for (int i = 0; i < 4; ++i) {
            acc[i].x = fmaf(alo[i], blo.x, acc[i].x);
            acc[i].y = fmaf(alo[i], blo.y, acc[i].y);
            acc[i].z = fmaf(alo[i], blo.z, acc[i].z);
            acc[i].w = fmaf(alo[i], blo.w, acc[i].w);
            acc[i].x = fmaf(ahi[i], bhi.x, acc[i].x);
            acc[i].y = fmaf(ahi[i], bhi.y, acc[i].y);
            acc[i].z = fmaf(ahi[i], bhi.z, acc[i].z);
            acc[i].w = fmaf(ahi[i], bhi.w, acc[i].w);
        }
    }

#pragma unroll
    for (int i = 0; i < 4; ++i) {
        int row = n0 + nodeLoc + i;
        if (row < n) {
            float dv = dinv[row];
            uint2 pk;
            pk.x = packbf2(acc[i].x * dv, acc[i].y * dv);
            pk.y = packbf2(acc[i].z * dv, acc[i].w * dv);
            *(uint2*)(out + (size_t)row * 64 + cg * 4) = pk;
        }
    }
}

// Final layer fused with output head:
// h3[j] = relu( b2[j] + dn*(ts[n][j] + sum ts[s][j]) ); out[n] = sigmoid(h3·Wo + bo)
__global__ void k_agg_out(const unsigned short* __restrict__ t, const float* __restrict__ dinv,
                          const int* __restrict__ rowstart, const int* __restrict__ cnt,
                          const int* __restrict__ col,
                          const float* __restrict__ b, const float* __restrict__ Wo,
                          const float* __restrict__ bo, float* __restrict__ out, int n) {
    const int gl  = threadIdx.x & 7;
    const int grp = threadIdx.x >> 3;
    const int gpb = blockDim.x >> 3;
    const float4 bv0 = ((const float4*)b)[gl * 2];
    const float4 bv1 = ((const float4*)b)[gl * 2 + 1];
    const float4 wv0 = ((const float4*)Wo)[gl * 2];
    const float4 wv1 = ((const float4*)Wo)[gl * 2 + 1];
    const float bo0 = bo[0];
    for (int node = blockIdx.x * gpb + grp; node < n; node += gpb * gridDim.x) {
        float dn = dinv[node];
        uint4 tv = *(const uint4*)(t + (size_t)node * 64 + gl * 8);
        float a0 = bflo(tv.x), a1 = bfhi(tv.x), a2 = bflo(tv.y), a3 = bfhi(tv.y);
        float a4 = bflo(tv.z), a5 = bfhi(tv.z), a6 = bflo(tv.w), a7 = bfhi(tv.w);
        int s0 = rowstart[node];
        int cpad = (cnt[node] + 7) & ~7;
        for (int base = 0; base < cpad; base += 8) {
            int myidx = col[s0 + base + gl];
#pragma unroll
            for (int j = 0; j < 8; ++j) {
                int s = __shfl(myidx, j, 8);
                uint4 g = *(const uint4*)(t + (size_t)s * 64 + gl * 8);
                a0 += bflo(g.x); a1 += bfhi(g.x);
                a2 += bflo(g.y); a3 += bfhi(g.y);
                a4 += bflo(g.z); a5 += bfhi(g.z);
                a6 += bflo(g.w); a7 += bfhi(g.w);
            }
        }
        float v = fmaxf(fmaf(a0, dn, bv0.x), 0.f) * wv0.x
                + fmaxf(fmaf(a1, dn, bv0.y), 0.f) * wv0.y
                + fmaxf(fmaf(a2, dn, bv0.z), 0.f) * wv0.z
                + fmaxf(fmaf(a3, dn, bv0.w), 0.f) * wv0.w
                + fmaxf(fmaf(a4, dn, bv1.x), 0.f) * wv1.x
                + fmaxf(fmaf(a5, dn, bv1.y), 0.f) * wv1.y
                + fmaxf(fmaf(a6, dn, bv1.z), 0.f) * wv1.z
                + fmaxf(fmaf(a7, dn, bv1.w), 0.f) * wv1.w;
#pragma unroll
        for (int off = 4; off > 0; off >>= 1) v += __shfl_xor(v, off, 8);
        if (gl == 0) out[node] = 1.0f / (1.0f + expf(-(v + bo0)));
    }
}

// ---------------- launch ----------------

extern "C" void kernel_launch(void* const* d_in, const int* in_sizes, int n_in,
                              void* d_out, int out_size, void* d_ws, size_t ws_size,
                              hipStream_t stream) {
    const float* x  = (const float*)d_in[0];
    const int*   ei = (const int*)d_in[1];
    const float* W0 = (const float*)d_in[2];
    const float* b0 = (const float*)d_in[3];
    const float* W1 = (const float*)d_in[4];
    const float* b1 = (const float*)d_in[5];
    const float* W2 = (const float*)d_in[6];
    const float* b2 = (const float*)d_in[7];
    const float* Wo = (const float*)d_in[8];
    const float* bo = (const float*)d_in[9];
    float* out = (float*)d_out;

    const int N = in_sizes[0] / 3;
    const int E = in_sizes[1] / 2;
    const int* src = ei;
    const int* dst = ei + E;
    const int nb = (N + VPB - 1) >> VSH;

    char* w = (char*)d_ws;
    size_t off = 0;
    auto take = [&](size_t bytes) -> void* {
        void* p = w + off;
        off = (off + bytes + 255) & ~(size_t)255;
        return p;
    };
    float* dinv     = (float*)take((size_t)N * 4);
    int*   cnt      = (int*)take((size_t)N * 4);
    int*   rowstart = (int*)take((size_t)N * 4);
    int*   gtotal   = (int*)take(4);
    int*   bktCur   = (int*)take(MAXB * 4);
    float* xw       = (float*)take((size_t)(N + 1) * 3 * 4);      // +sentinel row
    int*   col      = (int*)take(((size_t)E + 8 * (size_t)N) * 4); // padded CSR
    unsigned short* A  = (unsigned short*)take((size_t)(N + 1) * 64 * 2); // bf16 t1s (+sentinel)
    unsigned short* A2 = (unsigned short*)take((size_t)(N + 1) * 64 * 2); // bf16 t2s (+sentinel)
    int*   binned   = (int*)take((size_t)MAXB * CAP * 4);
    (void)ws_size; (void)n_in; (void)out_size;

    const int TB = 256;
    // graph prep: bin -> per-bucket padded CSR build (also emits dinv + xw)
    k_zero  <<<1, 256, 0, stream>>>(bktCur, gtotal, A + (size_t)N * 64,
                                    A2 + (size_t)N * 64, xw + (size_t)N * 3);
    k_bin   <<<(E + BINCH - 1) / BINCH, TB, 0, stream>>>(src, dst, bktCur, binned, E, nb);
    k_bucket<<<nb, VPB, 0, stream>>>(binned, bktCur, gtotal, rowstart, cnt, dinv, col, x, xw, N);

    // FUSED layer-0 agg + layer-0/1 GEMM -> bf16 A
    k_l01   <<<(N + GN2 - 1) / GN2, 256, 0, stream>>>(xw, dinv, rowstart, cnt, col,
                                                      W0, b0, W1, A, N);
    // FUSED layer-1 aggregation + layer-2 GEMM -> bf16 A2 (h2 never materialized)
    k_aggemm<<<(N + GN2 - 1) / GN2, 256, 0, stream>>>(A, dinv, rowstart, cnt, col,
                                                      b1, W2, A2, N);
    // layer-2 aggregation + output head
    k_agg_out<<<2048, TB, 0, stream>>>(A2, dinv, rowstart, cnt, col, b2, Wo, bo, out, N);
}